// Round 11
// baseline (135.021 us; speedup 1.0000x reference)
//
#include <hip/hip_runtime.h>

// out[b,i,j,d] = sum_{k<c} A[b,i,k,d] * B[b,k,j,d]   for i,j < c, else 0
// A: (256,64,64,32) f32, strides: b:131072, i:2048, k:32, d:1
// B: (256,64,64,32) f32, strides: b:131072, k:2048, j:32, d:1
//
// v11: v10's proven pieces (XCD-bucketed longest-first schedule + T19
// sched_group_barrier clustering) + float4 over d + K2 wide clusters.
//  - thread = (d4 0..7, j 0..63): B load + C store = contiguous 1KB/wave;
//    A load = 128B/instr + 8-way broadcast.
//  - per K2 group: [addr VALU][18 x global_load_dwordx4][64 FMA], ~116 VGPR
//    -> fits the launch_bounds(512,4) 128-VGPR cap so RA can't re-serialize
//    (v10's VGPR=64 showed the 48-scalar cluster was pressure-dropped).
// v10 result: 117 -> 79us from partial clustering alone; this doubles the
// bytes in flight per cluster and cuts VMEM+store instruction counts.

#define BATCH 256
#define NN 64
#define ND 32
#define BSTRIDE (NN * NN * ND)   // 131072 floats
#define RSTRIDE (NN * ND)        // 2048 floats
#define R4 (RSTRIDE / 4)         // 512 float4
#define ICHUNK 8
#define NITEMS (BATCH * (NN / ICHUNK))  // 2048, item w = b*8 + ic

// ---------------- prologue: per-XCD-bucket counting sort (v8, unchanged) ----
__global__ __launch_bounds__(512) void mp_prologue(
    const int* __restrict__ counts, int* __restrict__ items)
{
    __shared__ int cLds[BATCH];
    __shared__ int hist[8][NN + 1];  // key 0..63 = valid (64-c): whales first; 64 = zero-fill
    __shared__ int offs[8][NN + 1];
    const int tid = (int)threadIdx.x;

    for (int x = tid; x < 8 * (NN + 1); x += 512)
        (&hist[0][0])[x] = 0;
    for (int b = tid; b < BATCH; b += 512) cLds[b] = counts[b];
    __syncthreads();

    for (int w = tid; w < NITEMS; w += 512) {
        const int b = w >> 3, ic = w & 7;
        const int c = cLds[b];
        const int key = (ic * ICHUNK < c) ? (NN - c) : NN;
        atomicAdd(&hist[b & 7][key], 1);
    }
    __syncthreads();

    if (tid < 8) {  // serial 65-entry exclusive scan per bucket
        int acc = 0;
        for (int k = 0; k <= NN; ++k) { offs[tid][k] = acc; acc += hist[tid][k]; }
    }
    __syncthreads();

    for (int w = tid; w < NITEMS; w += 512) {
        const int b = w >> 3, ic = w & 7;
        const int c = cLds[b];
        const int key = (ic * ICHUNK < c) ? (NN - c) : NN;
        const int pos = atomicAdd(&offs[b & 7][key], 1);  // rank within bucket
        items[pos * 8 + (b & 7)] = w;                     // slot%8 == b%8
    }
}

// ---------------- main body: float4 + K2 cluster + sched_group_barrier ------
__device__ __forceinline__ void mp_body(
    int b, int ic,
    const float* __restrict__ A, const float* __restrict__ B,
    const int* __restrict__ counts, float* __restrict__ out)
{
    const int i0 = ic << 3;
    const int c  = counts[b];
    const int tid = (int)threadIdx.x;
    const int d4 = tid & 7;              // d float4-index: d = 4*d4 .. +3
    const int j  = tid >> 3;             // 0..63

    const size_t base = (size_t)b * BSTRIDE;
    float* __restrict__ Ob = out + base + (size_t)i0 * RSTRIDE + (size_t)j * ND + d4 * 4;

    if (i0 >= c) {
        const float4 z = make_float4(0.f, 0.f, 0.f, 0.f);
        #pragma unroll
        for (int ii = 0; ii < ICHUNK; ++ii)
            *reinterpret_cast<float4*>(Ob + (size_t)ii * RSTRIDE) = z;
        return;
    }

    const float4* __restrict__ A4 =
        reinterpret_cast<const float4*>(A + base + (size_t)i0 * RSTRIDE) + d4; // + ii*R4 + k*8
    const float4* __restrict__ B4 =
        reinterpret_cast<const float4*>(B + base + (size_t)j * ND) + d4;       // + k*R4

    float acc[ICHUNK][4];
    #pragma unroll
    for (int ii = 0; ii < ICHUNK; ++ii)
        #pragma unroll
        for (int dd = 0; dd < 4; ++dd)
            acc[ii][dd] = 0.0f;

    // wave w covers j in [8w, 8w+8); skip compute if entirely invalid
    const bool waveActive = (((tid >> 6) << 3) < c);

    if (waveActive) {
        const int c2 = c & ~1;
        int k = 0;
        #pragma unroll 1
        for (; k < c2; k += 2) {
            // phase 1: issue all 18 wide loads (2 k-steps)
            float4 av[2][ICHUNK];
            float4 bv[2];
            #pragma unroll
            for (int kk = 0; kk < 2; ++kk) {
                bv[kk] = B4[(size_t)(k + kk) * R4];
                #pragma unroll
                for (int ii = 0; ii < ICHUNK; ++ii)
                    av[kk][ii] = A4[(size_t)ii * R4 + (size_t)(k + kk) * (ND / 4)];
            }
            // phase 2: 64 FMAs
            #pragma unroll
            for (int kk = 0; kk < 2; ++kk)
                #pragma unroll
                for (int ii = 0; ii < ICHUNK; ++ii) {
                    acc[ii][0] = fmaf(av[kk][ii].x, bv[kk].x, acc[ii][0]);
                    acc[ii][1] = fmaf(av[kk][ii].y, bv[kk].y, acc[ii][1]);
                    acc[ii][2] = fmaf(av[kk][ii].z, bv[kk].z, acc[ii][2]);
                    acc[ii][3] = fmaf(av[kk][ii].w, bv[kk].w, acc[ii][3]);
                }

            // T19: pin [addr VALU][18 VMEM_READ][64 VALU] per K2 group.
            // Masks per LLVM SchedGroupMask: VALU=0x2, VMEM_READ=0x20.
            __builtin_amdgcn_sched_group_barrier(0x002, 8, 0);
            __builtin_amdgcn_sched_group_barrier(0x020, 18, 0);
            __builtin_amdgcn_sched_group_barrier(0x002, 64, 0);
        }
        // tail (<=1 iteration)
        if (k < c) {
            float4 bv = B4[(size_t)k * R4];
            #pragma unroll
            for (int ii = 0; ii < ICHUNK; ++ii) {
                float4 a = A4[(size_t)ii * R4 + (size_t)k * (ND / 4)];
                acc[ii][0] = fmaf(a.x, bv.x, acc[ii][0]);
                acc[ii][1] = fmaf(a.y, bv.y, acc[ii][1]);
                acc[ii][2] = fmaf(a.z, bv.z, acc[ii][2]);
                acc[ii][3] = fmaf(a.w, bv.w, acc[ii][3]);
            }
        }
    }

    // masked store (output poisoned before timing -> write everything)
    const bool jv = (j < c);
    #pragma unroll
    for (int ii = 0; ii < ICHUNK; ++ii) {
        const bool v = jv && ((i0 + ii) < c);
        const float4 o = v ? make_float4(acc[ii][0], acc[ii][1], acc[ii][2], acc[ii][3])
                           : make_float4(0.f, 0.f, 0.f, 0.f);
        *reinterpret_cast<float4*>(Ob + (size_t)ii * RSTRIDE) = o;
    }
}

__global__ __launch_bounds__(512, 4) void mp_kernel_sorted(
    const float* __restrict__ A, const float* __restrict__ B,
    const int* __restrict__ counts, float* __restrict__ out,
    const int* __restrict__ items)
{
    const int w = items[blockIdx.x];
    mp_body(w >> 3, w & 7, A, B, counts, out);
}

__global__ __launch_bounds__(512, 4) void mp_kernel_direct(
    const float* __restrict__ A, const float* __restrict__ B,
    const int* __restrict__ counts, float* __restrict__ out)
{
    mp_body(blockIdx.x & (BATCH - 1), blockIdx.x >> 8, A, B, counts, out);
}

extern "C" void kernel_launch(void* const* d_in, const int* in_sizes, int n_in,
                              void* d_out, int out_size, void* d_ws, size_t ws_size,
                              hipStream_t stream)
{
    const float* A      = (const float*)d_in[0];
    const float* B      = (const float*)d_in[1];
    const int*   counts = (const int*)d_in[2];
    float* out = (float*)d_out;

    if (ws_size >= NITEMS * sizeof(int)) {
        int* items = (int*)d_ws;
        mp_prologue<<<dim3(1), dim3(512), 0, stream>>>(counts, items);
        mp_kernel_sorted<<<dim3(NITEMS), dim3(512), 0, stream>>>(A, B, counts, out, items);
    } else {
        mp_kernel_direct<<<dim3(NITEMS), dim3(512), 0, stream>>>(A, B, counts, out);
    }
}

// Round 12
// 79.790 us; speedup vs baseline: 1.6922x; 1.6922x over previous
//
#include <hip/hip_runtime.h>

// out[b,i,j,d] = sum_{k<c} A[b,i,k,d] * B[b,k,j,d]   for i,j < c, else 0
// A: (256,64,64,32) f32, strides: b:131072, i:2048, k:32, d:1
// B: (256,64,64,32) f32, strides: b:131072, k:2048, j:32, d:1
//
// v12: cross-iteration software pipeline (the v10 lesson taken to its
// conclusion). v10/v11 clustered loads and uses within ONE iteration ->
// first-load latency exposed per group; v11's wide loads blew the VGPR
// budget (demand ~104, RA refused, clustering collapsed, 135us).
// Here: v10's proven (d, jg) scalar mapping, K2 groups (24 scalar loads,
// 24 VGPR/group), double-buffered in registers; group g+1's loads issue
// BEFORE group g's FMAs -> steady-state waitcnt is vmcnt(24), zero exposed
// latency. Demand ~95 VGPR < 128 cap. SGB pins [24 VMEM_READ][64 VALU].
// Schedule/prologue identical to v8/v10 (XCD-bucketed longest-first sort).

#define BATCH 256
#define NN 64
#define ND 32
#define BSTRIDE (NN * NN * ND)   // 131072
#define RSTRIDE (NN * ND)        // 2048
#define ICHUNK 8
#define NITEMS (BATCH * (NN / ICHUNK))  // 2048, item w = b*8 + ic

// ---------------- prologue: per-XCD-bucket counting sort (v8, unchanged) ----
__global__ __launch_bounds__(512) void mp_prologue(
    const int* __restrict__ counts, int* __restrict__ items)
{
    __shared__ int cLds[BATCH];
    __shared__ int hist[8][NN + 1];  // key 0..63 = valid (64-c): whales first; 64 = zero-fill
    __shared__ int offs[8][NN + 1];
    const int tid = (int)threadIdx.x;

    for (int x = tid; x < 8 * (NN + 1); x += 512)
        (&hist[0][0])[x] = 0;
    for (int b = tid; b < BATCH; b += 512) cLds[b] = counts[b];
    __syncthreads();

    for (int w = tid; w < NITEMS; w += 512) {
        const int b = w >> 3, ic = w & 7;
        const int c = cLds[b];
        const int key = (ic * ICHUNK < c) ? (NN - c) : NN;
        atomicAdd(&hist[b & 7][key], 1);
    }
    __syncthreads();

    if (tid < 8) {  // serial 65-entry exclusive scan per bucket
        int acc = 0;
        for (int k = 0; k <= NN; ++k) { offs[tid][k] = acc; acc += hist[tid][k]; }
    }
    __syncthreads();

    for (int w = tid; w < NITEMS; w += 512) {
        const int b = w >> 3, ic = w & 7;
        const int c = cLds[b];
        const int key = (ic * ICHUNK < c) ? (NN - c) : NN;
        const int pos = atomicAdd(&offs[b & 7][key], 1);  // rank within bucket
        items[pos * 8 + (b & 7)] = w;                     // slot%8 == b%8
    }
}

// group load: 2 k-steps (24 scalar loads) into register buffers
#define LOADG(AV, BV, K0)                                                      \
    {                                                                          \
        _Pragma("unroll")                                                      \
        for (int kk = 0; kk < 2; ++kk) {                                       \
            _Pragma("unroll")                                                  \
            for (int ii = 0; ii < ICHUNK; ++ii)                                \
                AV[kk][ii] = Ai[(size_t)ii * RSTRIDE + (size_t)((K0) + kk) * ND]; \
            _Pragma("unroll")                                                  \
            for (int jj = 0; jj < 4; ++jj)                                     \
                BV[kk][jj] = Bb[(size_t)((K0) + kk) * RSTRIDE + jj * ND];      \
        }                                                                      \
    }

// group FMA: 64 fmas consuming one buffer pair
#define FMAG(AV, BV)                                                           \
    {                                                                          \
        _Pragma("unroll")                                                      \
        for (int kk = 0; kk < 2; ++kk)                                         \
            _Pragma("unroll")                                                  \
            for (int ii = 0; ii < ICHUNK; ++ii)                                \
                _Pragma("unroll")                                              \
                for (int jj = 0; jj < 4; ++jj)                                 \
                    acc[ii][jj] = fmaf(AV[kk][ii], BV[kk][jj], acc[ii][jj]);   \
    }

// T19: pin [24 VMEM_READ][64 VALU] per half-iteration (VALU=0x2, VMEM_READ=0x20)
#define SGB2                                                                   \
    {                                                                          \
        __builtin_amdgcn_sched_group_barrier(0x020, 24, 0);                    \
        __builtin_amdgcn_sched_group_barrier(0x002, 64, 0);                    \
    }

// ---------------- main body: 2-deep register pipeline ----------------------
__device__ __forceinline__ void mp_body(
    int b, int ic,
    const float* __restrict__ A, const float* __restrict__ B,
    const int* __restrict__ counts, float* __restrict__ out)
{
    const int i0 = ic << 3;
    const int c  = counts[b];
    const int tid = (int)threadIdx.x;
    const int d  = tid & 31;             // channel
    const int jg = tid >> 5;             // 0..15, group of 4 j's
    const int jb = jg << 2;              // j base

    const size_t base = (size_t)b * BSTRIDE;
    float* __restrict__ Ob = out + base + (size_t)i0 * RSTRIDE + (size_t)jb * ND + d;

    if (i0 >= c) {
        #pragma unroll
        for (int ii = 0; ii < ICHUNK; ++ii)
            #pragma unroll
            for (int jj = 0; jj < 4; ++jj)
                Ob[(size_t)ii * RSTRIDE + jj * ND] = 0.0f;
        return;
    }

    const float* __restrict__ Ai = A + base + (size_t)i0 * RSTRIDE + d;
    const float* __restrict__ Bb = B + base + (size_t)jb * ND + d;

    float acc[ICHUNK][4];
    #pragma unroll
    for (int ii = 0; ii < ICHUNK; ++ii)
        #pragma unroll
        for (int jj = 0; jj < 4; ++jj)
            acc[ii][jj] = 0.0f;

    const bool waveActive = (((tid >> 6) << 3) < c);

    if (waveActive) {
        const int c2 = c & ~1;
        const int ng = c2 >> 1;          // K2 groups
        float aA[2][ICHUNK], bA[2][4];   // ping
        float aB[2][ICHUNK], bB[2][4];   // pong

        if (ng >= 1) {
            LOADG(aA, bA, 0);
            int g = 0;
            #pragma unroll 1
            while (g + 2 <= ng) {
                LOADG(aB, bB, g * 2 + 2);        // prefetch group g+1
                FMAG(aA, bA);                     // consume group g
                SGB2;
                const int kn = (g + 2 < ng) ? (g * 2 + 4) : 0;  // clamp: dummy, rows 0..1 always valid
                LOADG(aA, bA, kn);                // prefetch group g+2 (or dummy)
                FMAG(aB, bB);                     // consume group g+1
                SGB2;
                g += 2;
            }
            if (g < ng) {                         // odd ng: last group in ping
                FMAG(aA, bA);
            }
        }
        // odd-c tail: single k = c2
        if (c & 1) {
            const int k = c2;
            float av[ICHUNK];
            #pragma unroll
            for (int ii = 0; ii < ICHUNK; ++ii)
                av[ii] = Ai[(size_t)ii * RSTRIDE + (size_t)k * ND];
            float bv[4];
            #pragma unroll
            for (int jj = 0; jj < 4; ++jj)
                bv[jj] = Bb[(size_t)k * RSTRIDE + jj * ND];
            #pragma unroll
            for (int ii = 0; ii < ICHUNK; ++ii)
                #pragma unroll
                for (int jj = 0; jj < 4; ++jj)
                    acc[ii][jj] = fmaf(av[ii], bv[jj], acc[ii][jj]);
        }
    }

    #pragma unroll
    for (int ii = 0; ii < ICHUNK; ++ii) {
        const bool iv = (i0 + ii) < c;
        #pragma unroll
        for (int jj = 0; jj < 4; ++jj) {
            const bool v = iv && ((jb + jj) < c);
            Ob[(size_t)ii * RSTRIDE + jj * ND] = v ? acc[ii][jj] : 0.0f;
        }
    }
}

__global__ __launch_bounds__(512, 4) void mp_kernel_sorted(
    const float* __restrict__ A, const float* __restrict__ B,
    const int* __restrict__ counts, float* __restrict__ out,
    const int* __restrict__ items)
{
    const int w = items[blockIdx.x];
    mp_body(w >> 3, w & 7, A, B, counts, out);
}

__global__ __launch_bounds__(512, 4) void mp_kernel_direct(
    const float* __restrict__ A, const float* __restrict__ B,
    const int* __restrict__ counts, float* __restrict__ out)
{
    mp_body(blockIdx.x & (BATCH - 1), blockIdx.x >> 8, A, B, counts, out);
}

extern "C" void kernel_launch(void* const* d_in, const int* in_sizes, int n_in,
                              void* d_out, int out_size, void* d_ws, size_t ws_size,
                              hipStream_t stream)
{
    const float* A      = (const float*)d_in[0];
    const float* B      = (const float*)d_in[1];
    const int*   counts = (const int*)d_in[2];
    float* out = (float*)d_out;

    if (ws_size >= NITEMS * sizeof(int)) {
        int* items = (int*)d_ws;
        mp_prologue<<<dim3(1), dim3(512), 0, stream>>>(counts, items);
        mp_kernel_sorted<<<dim3(NITEMS), dim3(512), 0, stream>>>(A, B, counts, out, items);
    } else {
        mp_kernel_direct<<<dim3(NITEMS), dim3(512), 0, stream>>>(A, B, counts, out);
    }
}